// Round 6
// baseline (40.385 us; speedup 1.0000x reference)
//
#include <hip/hip_runtime.h>
#include <math.h>

#define THREADS 1024
#define NFFT 16384      // complex FFT length: 2 real rows packed as re/im
#define MIN_IDX 364     // argmin |f - 40/60|, exact fp32 (f[k]=k*15/8192 is exact)
#define MAX_IDX 2276    // argmin |f - 250/60|, exact fp32

__device__ __forceinline__ int br12(int x) {
    return (int)(__brev((unsigned)x) >> 20);
}

// Element p is stored at cf[PHI(p)]. XOR bits 8..10 of p into bits 1..3:
// - preserves bit 0 -> float4 pairs (even p, p+1) stay contiguous & 16B-aligned
// - rounds A/B: bits 8..10 are wave-constant -> pure bank permutation (free)
// - round C: injects lane bits 4..5 -> <=2-way on b64 (free, m136)
// - untangle: a = br12(k) = 64*rev6(lane-bits)+c, so (p>>8)&7 = rev6 low bits
//   -> 64 lanes spread uniformly over all eight 16B slots (conflict-free b128)
__device__ __forceinline__ int PHI(int p) {
    return p ^ (((p >> 8) & 7) << 1);
}

// exp(-2*pi*i*f), f in revolutions (v_sin/cos_f32 native domain), f in [0,0.07]
__device__ __forceinline__ float2 wtw(float f) {
    return make_float2(__builtin_amdgcn_cosf(f), -__builtin_amdgcn_sinf(f));
}

__device__ __forceinline__ float2 cmul(float2 a, float2 b) {
    return make_float2(a.x * b.x - a.y * b.y, a.x * b.y + a.y * b.x);
}

// DIF butterfly: (a,b) -> (a+b, (a-b)*tw)
__device__ __forceinline__ void bfly(float2& a, float2& b, float2 tw) {
    float2 t = make_float2(a.x - b.x, a.y - b.y);
    a.x += b.x; a.y += b.y;
    b = cmul(t, tw);
}

// Four radix-2 DIF stages on 16 regs. v[m] = position base+stride*m of a
// length-L sub-FFT (stride = L/16); W1 = exp(-2*pi*i*base/L).
__device__ __forceinline__ void fft_block16(float2 v[16], float2 W1)
{
    // C16[m] = exp(-2*pi*i*m/16)
    constexpr float C16x[8] = {1.f,  0.92387953251128674f,  0.70710678118654757f,  0.38268343236508978f,
                               0.f, -0.38268343236508978f, -0.70710678118654757f, -0.92387953251128674f};
    constexpr float C16y[8] = {0.f, -0.38268343236508978f, -0.70710678118654757f, -0.92387953251128674f,
                              -1.f, -0.92387953251128674f, -0.70710678118654757f, -0.38268343236508978f};
    // C8[m] = exp(-2*pi*i*m/8)
    constexpr float C8x[4] = {1.f,  0.70710678118654757f,  0.f, -0.70710678118654757f};
    constexpr float C8y[4] = {0.f, -0.70710678118654757f, -1.f, -0.70710678118654757f};

    float2 W2 = cmul(W1, W1), W4 = cmul(W2, W2), W8 = cmul(W4, W4);

    #pragma unroll
    for (int m = 0; m < 8; ++m) {
        float2 tw = cmul(W1, make_float2(C16x[m], C16y[m]));
        bfly(v[m], v[m + 8], tw);
    }
    #pragma unroll
    for (int g = 0; g < 2; ++g) {
        #pragma unroll
        for (int m = 0; m < 4; ++m) {
            float2 tw = cmul(W2, make_float2(C8x[m], C8y[m]));
            bfly(v[8 * g + m], v[8 * g + m + 4], tw);
        }
    }
    float2 W4i = make_float2(W4.y, -W4.x);
    #pragma unroll
    for (int g = 0; g < 4; ++g) {
        bfly(v[4 * g + 0], v[4 * g + 2], W4);
        bfly(v[4 * g + 1], v[4 * g + 3], W4i);
    }
    #pragma unroll
    for (int g = 0; g < 8; ++g)
        bfly(v[2 * g], v[2 * g + 1], W8);
}

// analytic argmin_k |k*step - t|, ascending candidates, strict < (first-index ties)
__device__ __forceinline__ int ref_idx(float t_hz) {
    const float step = 15.0f / 8192.0f;
    int kf = (int)floorf(t_hz * (8192.0f / 15.0f));
    int ri = 0; float best = 1e30f;
    #pragma unroll
    for (int d = -1; d <= 2; ++d) {
        int k = min(max(kf + d, 0), 8192);
        float dist = fabsf((float)k * step - t_hz);
        if (dist < best) { best = dist; ri = k; }
    }
    return ri;
}

// One block per ROW PAIR (rowA=2b real, rowB=2b+1 imag). 128 KiB LDS, 1 blk/CU.
__global__ __launch_bounds__(THREADS, 4)
void negsnr_pair_kernel(const float* __restrict__ x,
                        const float* __restrict__ targets,
                        float* __restrict__ snr_out)
{
    __shared__ float2 cf[NFFT];    // 131072 bytes
    const int pair = blockIdx.x;
    const int tid  = threadIdx.x;
    const int lane = tid & 63;
    const int wave = tid >> 6;

    // ---- issue global loads first (overlap with ref_idx) ----
    const float* ra = x + (size_t)(2 * pair) * NFFT;
    const float* rb = ra + NFFT;
    float2 v[16];
    #pragma unroll
    for (int m = 0; m < 16; ++m) {
        v[m].x = ra[tid + 1024 * m];
        v[m].y = rb[tid + 1024 * m];
    }

    const int riA = ref_idx(targets[2 * pair]     / 60.0f);
    const int riB = ref_idx(targets[2 * pair + 1] / 60.0f);

    // ---- Round A: stride 1024, stages h=8192..1024, W1 = W_16384^tid ----
    fft_block16(v, wtw((float)tid * (1.0f / 16384.0f)));
    #pragma unroll
    for (int m = 0; m < 16; ++m) cf[PHI(tid + 1024 * m)] = v[m];
    __syncthreads();

    // ---- Round B: 16 chunks of 1024, stride 64; wave == chunk ----
    {
        const int q = tid & 63, base = q + ((tid >> 6) << 10);
        #pragma unroll
        for (int m = 0; m < 16; ++m) v[m] = cf[PHI(base + 64 * m)];
        fft_block16(v, wtw((float)q * (1.0f / 1024.0f)));
        #pragma unroll
        for (int m = 0; m < 16; ++m) cf[PHI(base + 64 * m)] = v[m];
    }
    __syncthreads();

    // ---- Round C: 256 chunks of 64, stride 4 ----
    {
        const int q2 = tid & 3, base = q2 + ((tid >> 2) << 6);
        #pragma unroll
        for (int m = 0; m < 16; ++m) v[m] = cf[PHI(base + 4 * m)];
        fft_block16(v, wtw((float)q2 * (1.0f / 64.0f)));
        #pragma unroll
        for (int m = 0; m < 16; ++m) cf[PHI(base + 4 * m)] = v[m];
    }
    __syncthreads();
    // cf holds Y after stages down to h=4. Remaining h=2 (tw {1,-i}) and h=1
    // (tw 1) are folded below: position 4a+r holds Z[rev2(r)*4096 + rev12(a)]:
    //   Z[rev12(a)]        = I0+I1+I2+I3
    //   Z[12288+rev12(a)]  = (I0-I2) - (-i)(I1-I3)
    // where I[j] = Y[4a+j].

    // ---- Untangle: for k in [364,2276): Z[k] and Z[16384-k], both rows' P1 ----
    float oA = 0.0f, oB = 0.0f, pA = 0.0f, pB = 0.0f;
    bool hA = false, hB = false;
    for (int k = MIN_IDX + tid; k < MAX_IDX; k += THREADS) {
        const int a  = br12(k);             // Z[k] = O0 of group a
        const int a2 = br12(4096 - k);      // Z[16384-k] = O3 of group a2
        const int s1 = ((a  >> 6) & 7) << 1;
        const int s2 = ((a2 >> 6) & 7) << 1;
        float4 u01 = *(const float4*)&cf[(4 * a)     ^ s1];   // I0,I1
        float4 u23 = *(const float4*)&cf[(4 * a + 2) ^ s1];   // I2,I3
        float4 w01 = *(const float4*)&cf[(4 * a2)     ^ s2];
        float4 w23 = *(const float4*)&cf[(4 * a2 + 2) ^ s2];

        float Zr = u01.x + u01.z + u23.x + u23.z;
        float Zi = u01.y + u01.w + u23.y + u23.w;
        float d02r = w01.x - w23.x, d02i = w01.y - w23.y;
        float d13r = w01.z - w23.z, d13i = w01.w - w23.w;
        float Zmr = d02r - d13i;            // O3 = (I0-I2) - (-i)(I1-I3)
        float Zmi = d02i + d13r;

        // A = Z + conj(Zm); B = -i(Z - conj(Zm)); constant 1/2 etc. cancels
        float Ar = Zr + Zmr, Ai = Zi - Zmi;
        float Br = Zr - Zmr, Bi = Zi + Zmi;
        float PA = Ar * Ar + Ai * Ai;
        float PB = Br * Br + Bi * Bi;

        if (k < riA - 1 || k > riA + 1) oA += PA;
        if (k == riA) { pA = PA; hA = true; }
        if (k < riB - 1 || k > riB + 1) oB += PB;
        if (k == riB) { pB = PB; hB = true; }
    }
    __syncthreads();                 // all cf reads done; reuse as scratch
    if (hA) cf[16].x = pA;           // ri in [409,1776]: exactly one writer each
    if (hB) cf[16].y = pB;
    #pragma unroll
    for (int off = 32; off; off >>= 1) {
        oA += __shfl_down(oA, off);
        oB += __shfl_down(oB, off);
    }
    if (lane == 0) { cf[wave].x = oA; cf[wave].y = oB; }
    __syncthreads();
    if (tid == 0) {
        float tA = 0.0f, tB = 0.0f;
        #pragma unroll
        for (int w = 0; w < 16; ++w) { tA += cf[w].x; tB += cf[w].y; }
        const float denom = (float)(MAX_IDX - MIN_IDX - 3);   // 1909
        snr_out[2 * pair]     = 10.0f * log10f(cf[16].x * denom / tA);
        snr_out[2 * pair + 1] = 10.0f * log10f(cf[16].y * denom / tB);
    }
}

__global__ void negsnr_mean_kernel(const float* __restrict__ snr,
                                   float* __restrict__ out, int n)
{
    __shared__ float sacc[4];
    const int tid = threadIdx.x;
    float acc = 0.0f;
    for (int i = tid; i < n; i += 256) acc += snr[i];
    #pragma unroll
    for (int off = 32; off; off >>= 1) acc += __shfl_down(acc, off);
    if ((tid & 63) == 0) sacc[tid >> 6] = acc;
    __syncthreads();
    if (tid == 0) {
        float t = sacc[0] + sacc[1] + sacc[2] + sacc[3];
        out[0] = -t / (float)n;
    }
}

extern "C" void kernel_launch(void* const* d_in, const int* in_sizes, int n_in,
                              void* d_out, int out_size, void* d_ws, size_t ws_size,
                              hipStream_t stream) {
    const float* outputs = (const float*)d_in[0];
    const float* targets = (const float*)d_in[1];
    const int B = in_sizes[1];                 // 1024 rows
    float* snr = (float*)d_ws;                 // B floats of scratch

    negsnr_pair_kernel<<<B / 2, THREADS, 0, stream>>>(outputs, targets, snr);
    negsnr_mean_kernel<<<1, 256, 0, stream>>>(snr, (float*)d_out, B);
}

// Round 7
// 34.638 us; speedup vs baseline: 1.1659x; 1.1659x over previous
//
#include <hip/hip_runtime.h>
#include <math.h>

#define THREADS 512
#define MHALF 8192      // complex FFT length (N/2)
#define NREAL 16384
#define MIN_IDX 364     // argmin |f - 40/60|, exact fp32 (f[k]=k*15/8192 is exact)
#define MAX_IDX 2276    // argmin |f - 250/60|, exact fp32

__device__ __forceinline__ int br13(int x) {
    return (int)(__brev((unsigned)x) >> 19);
}

// Element p lives at cf[PHI(p)]. Inject p's bits 7..9 into the 16B-slot bits
// 1..3. Rationale: untangle reads use a = br13(k) whose LANE-varying bits are
// 7..12 (rev6(lane)); injecting bits 7..9 (= lane bits 5,4,3) spreads each
// wave's 64 float4 reads uniformly over the eight 16B slots -> conflict-free
// b128 (was ~16-way with the old (p>>5) swizzle = the 1.25e7 counter).
// Desk-checked per phase: B1 store wave-uniform XOR (free); B2 4 lanes/slot
// (2/bank, free); B3 8 lanes/slot (4-way, 1.58x on that phase only);
// untangle a- and b-streams uniform (free). Preserves bit 0; PHI(p)+1 ==
// PHI(p+1) for even p -> float4 pairs stay contiguous & 16B-aligned.
__device__ __forceinline__ int PHI(int p) {
    return p ^ (((p >> 7) & 7) << 1);
}

// exp(-2*pi*i*f), f in revolutions. v_sin_f32/v_cos_f32 take revolutions
// (D = sin(S0*2pi)); our f is in [0, 0.2] so no range reduction needed.
// Twiddle abs error ~1e-6 -> far below the task's tolerance.
__device__ __forceinline__ float2 wtw(float f) {
    return make_float2(__builtin_amdgcn_cosf(f), -__builtin_amdgcn_sinf(f));
}

__device__ __forceinline__ float2 cmul(float2 a, float2 b) {
    return make_float2(a.x * b.x - a.y * b.y, a.x * b.y + a.y * b.x);
}

// DIF butterfly: (a,b) -> (a+b, (a-b)*tw)
__device__ __forceinline__ void bfly(float2& a, float2& b, float2 tw) {
    float2 t = make_float2(a.x - b.x, a.y - b.y);
    a.x += b.x; a.y += b.y;
    b = cmul(t, tw);
}

// Four radix-2 DIF stages on 16 regs. v[m] holds virtual position base+stride*m
// of a length-L sub-FFT (stride = L/16); W1 = exp(-2*pi*i*base/L).
__device__ __forceinline__ void fft_block16(float2 v[16], float2 W1)
{
    // C16[m] = exp(-2*pi*i*m/16) (16th roots of unity)
    constexpr float C16x[8] = {1.f,  0.92387953251128674f,  0.70710678118654757f,  0.38268343236508978f,
                               0.f, -0.38268343236508978f, -0.70710678118654757f, -0.92387953251128674f};
    constexpr float C16y[8] = {0.f, -0.38268343236508978f, -0.70710678118654757f, -0.92387953251128674f,
                              -1.f, -0.92387953251128674f, -0.70710678118654757f, -0.38268343236508978f};
    // C8[m] = exp(-2*pi*i*m/8)
    constexpr float C8x[4] = {1.f,  0.70710678118654757f,  0.f, -0.70710678118654757f};
    constexpr float C8y[4] = {0.f, -0.70710678118654757f, -1.f, -0.70710678118654757f};

    float2 W2 = cmul(W1, W1), W4 = cmul(W2, W2), W8 = cmul(W4, W4);

    // stage A: pairs (m, m+8), tw = W1 * C16[m]
    #pragma unroll
    for (int m = 0; m < 8; ++m) {
        float2 tw = cmul(W1, make_float2(C16x[m], C16y[m]));
        bfly(v[m], v[m + 8], tw);
    }
    // stage B: pairs (idx, idx+4) in groups of 8, tw = W2 * C8[m]
    #pragma unroll
    for (int g = 0; g < 2; ++g) {
        #pragma unroll
        for (int m = 0; m < 4; ++m) {
            float2 tw = cmul(W2, make_float2(C8x[m], C8y[m]));
            bfly(v[8 * g + m], v[8 * g + m + 4], tw);
        }
    }
    // stage C: pairs (idx, idx+2) in groups of 4, tw = W4 * {1, -i}
    float2 W4i = make_float2(W4.y, -W4.x);
    #pragma unroll
    for (int g = 0; g < 4; ++g) {
        bfly(v[4 * g + 0], v[4 * g + 2], W4);
        bfly(v[4 * g + 1], v[4 * g + 3], W4i);
    }
    // stage D: pairs (2g, 2g+1), tw = W8
    #pragma unroll
    for (int g = 0; g < 8; ++g)
        bfly(v[2 * g], v[2 * g + 1], W8);
}

// One block per row. LDS: exactly 64 KiB -> 2 blocks/CU.
__global__ __launch_bounds__(THREADS, 2)
void negsnr_row_kernel(const float* __restrict__ x,
                       const float* __restrict__ targets,
                       float* __restrict__ snr_out)
{
    __shared__ float2 cf[MHALF];   // 65536 bytes
    const int row  = blockIdx.x;
    const int tid  = threadIdx.x;
    const int lane = tid & 63;
    const int wave = tid >> 6;

    // ---- Issue the 16 global loads FIRST (overlap latency with phase 0) ----
    const float2* xr = (const float2*)(x + (size_t)row * NREAL);
    float2 v[16];
    #pragma unroll
    for (int m = 0; m < 16; ++m) v[m] = xr[tid + 512 * m];

    // ---- Phase 0: ref_idx, analytic (4 candidates), exact fp32 replication ----
    const float step = 15.0f / 8192.0f;            // exact in fp32
    const float t_hz = targets[row] / 60.0f;       // fp32 divide, same as reference
    int ri;
    {
        int kf = (int)floorf(t_hz * (8192.0f / 15.0f));
        float best = 1e30f; ri = 0;
        #pragma unroll
        for (int d = -1; d <= 2; ++d) {            // ascending k, strict < => first-index ties
            int k = min(max(kf + d, 0), 8192);
            float dist = fabsf((float)k * step - t_hz);
            if (dist < best) { best = dist; ri = k; }
        }
    }

    // ---- Block 1: stages 0-3 (stride 512), regs -> LDS ----
    fft_block16(v, wtw((float)tid * (1.0f / 8192.0f)));
    #pragma unroll
    for (int m = 0; m < 16; ++m) cf[PHI(tid + 512 * m)] = v[m];
    __syncthreads();

    // ---- Block 2: stride 32 within 512-chunks, stages 4-7 ----
    const int low5 = tid & 31;
    const int base2 = low5 + ((tid >> 5) << 9);
    #pragma unroll
    for (int m = 0; m < 16; ++m) v[m] = cf[PHI(base2 + 32 * m)];
    fft_block16(v, wtw((float)low5 * (1.0f / 512.0f)));
    #pragma unroll
    for (int m = 0; m < 16; ++m) cf[PHI(base2 + 32 * m)] = v[m];
    __syncthreads();

    // ---- Block 3: stride 2, stages 8-11 (base twiddle constant per parity) ----
    const int p = tid & 1;
    const int base3 = p + ((tid >> 1) << 5);
    #pragma unroll
    for (int m = 0; m < 16; ++m) v[m] = cf[PHI(base3 + 2 * m)];
    {
        float2 U = p ? make_float2(0.98078528040323044f, -0.19509032201612825f)  // exp(-i*pi/16)
                     : make_float2(1.0f, 0.0f);
        fft_block16(v, U);
    }
    #pragma unroll
    for (int m = 0; m < 16; ++m) cf[PHI(base3 + 2 * m)] = v[m];
    __syncthreads();
    // LDS holds Y = FFT through stage 11. Stage 12 (tw=1) folded below:
    // even a: Z[a] = Y[a]+Y[a+1]; odd b: Z[b] = Y[b-1]-Y[b]; X[k] = Z[br13(k)].

    // ---- Phase 3: rfft untangle for k in [364,2276), P1, masked sum ----
    float other = 0.0f, pulse = 0.0f;
    bool hasp = false;
    for (int k = MIN_IDX + tid; k < MAX_IDX; k += THREADS) {
        int a = br13(k);              // even (k < 4096)
        int b = br13(MHALF - k);      // odd  (8192-k >= 4096)
        float4 ya = *(const float4*)&cf[PHI(a)];       // Y[a], Y[a+1]
        float4 yb = *(const float4*)&cf[PHI(b - 1)];   // Y[b-1], Y[b]
        float Zr  = ya.x + ya.z, Zi  = ya.y + ya.w;    // Z[k]
        float Zmr = yb.x - yb.z, Zmi = yb.y - yb.w;    // Z[8192-k]
        // Xe = (Z + conj(Zm))/2 ; Xo = (Z - conj(Zm))/(2i); X = Xe + W_N^k * Xo
        float xer  = 0.5f * (Zr + Zmr), xei = 0.5f * (Zi - Zmi);
        float xor_ = 0.5f * (Zi + Zmi), xoi = -0.5f * (Zr - Zmr);
        float2 tw = wtw((float)k * (1.0f / 16384.0f));
        float xr_ = xer + tw.x * xor_ - tw.y * xoi;
        float xi_ = xei + tw.x * xoi + tw.y * xor_;
        float pw = xr_ * xr_ + xi_ * xi_;
        if (k < ri - 1 || k > ri + 1) other += pw;     // mask: [364,ri-1) U [ri+2,2276)
        if (k == ri) { pulse = pw; hasp = true; }
    }
    __syncthreads();                 // all cf reads done; reuse as reduction scratch
    if (hasp) cf[8].x = pulse;       // exactly one writer (ri in [409,1776])
    #pragma unroll
    for (int off = 32; off; off >>= 1) other += __shfl_down(other, off);
    if (lane == 0) cf[wave].x = other;
    __syncthreads();
    if (tid == 0) {
        float tot = 0.0f;
        #pragma unroll
        for (int w = 0; w < 8; ++w) tot += cf[w].x;
        const float denom = (float)(MAX_IDX - MIN_IDX - 3);   // 1909
        snr_out[row] = 10.0f * log10f(cf[8].x * denom / tot);
    }
}

__global__ void negsnr_mean_kernel(const float* __restrict__ snr,
                                   float* __restrict__ out, int n)
{
    __shared__ float sacc[4];
    const int tid = threadIdx.x;
    float acc = 0.0f;
    for (int i = tid; i < n; i += 256) acc += snr[i];
    #pragma unroll
    for (int off = 32; off; off >>= 1) acc += __shfl_down(acc, off);
    if ((tid & 63) == 0) sacc[tid >> 6] = acc;
    __syncthreads();
    if (tid == 0) {
        float t = sacc[0] + sacc[1] + sacc[2] + sacc[3];
        out[0] = -t / (float)n;
    }
}

extern "C" void kernel_launch(void* const* d_in, const int* in_sizes, int n_in,
                              void* d_out, int out_size, void* d_ws, size_t ws_size,
                              hipStream_t stream) {
    const float* outputs = (const float*)d_in[0];
    const float* targets = (const float*)d_in[1];
    const int B = in_sizes[1];                 // 1024 rows
    float* snr = (float*)d_ws;                 // B floats of scratch

    negsnr_row_kernel<<<B, THREADS, 0, stream>>>(outputs, targets, snr);
    negsnr_mean_kernel<<<1, 256, 0, stream>>>(snr, (float*)d_out, B);
}